// Round 5
// baseline (993.325 us; speedup 1.0000x reference)
//
#include <hip/hip_runtime.h>

typedef unsigned short ushort_t;
typedef __attribute__((ext_vector_type(8))) short short8;   // 8 bf16 (4 VGPRs)
typedef __attribute__((ext_vector_type(4))) float floatx4;  // 4 fp32 acc

#define B_  4
#define T_  2048
#define C_  512
#define H_  8
#define HS_ 64
#define M_  (B_*T_)          // 8192 rows
#define SCALE 0.04419417382415922f  // 512^-0.5
#define NEG_BIG (-3.0e4f)

__device__ __forceinline__ float b2f(ushort_t u) {
  union { unsigned int i; float f; } w; w.i = ((unsigned int)u) << 16; return w.f;
}
__device__ __forceinline__ ushort_t f2b(float f) {
  union { float f; unsigned int i; } w; w.f = f;
  unsigned int x = w.i;
  return (ushort_t)((x + 0x7fffu + ((x >> 16) & 1u)) >> 16);  // RNE
}
__device__ __forceinline__ float loadx(const void* p, size_t i, int isf32) {
  return isf32 ? ((const float*)p)[i] : b2f(((const ushort_t*)p)[i]);
}

// ---- input dtype detector: flag[0]=1 iff inputs are fp32 containers ------
// flag[1]=1 (always-fp32 path for internal fp32 buffers)
__global__ void detect_k(const ushort_t* __restrict__ xraw,
                         int* __restrict__ flag) {
  __shared__ int bad, lowzero;
  if (threadIdx.x == 0) { bad = 0; lowzero = 0; }
  __syncthreads();
  int b = 0, z = 0;
  for (int i = threadIdx.x; i < 16384; i += 256) {
    ushort_t u = xraw[i];
    if (((u >> 7) & 0xFF) == 0xFF) b++;          // bf16 NaN/Inf pattern
    if (((i & 1) == 0) && (u == 0)) z++;         // zero low halfword (LE fp32)
  }
  atomicAdd(&bad, b); atomicAdd(&lowzero, z);
  __syncthreads();
  if (threadIdx.x == 0) {
    flag[0] = (bad > 0 || lowzero > 6000) ? 1 : 0;
    flag[1] = 1;
  }
}

// ---- LayerNorm: wave per row of 512. X dtype via flagX, g/b via flagP ----
__global__ __launch_bounds__(256) void ln_k(const void* __restrict__ X,
                                            const void* __restrict__ g,
                                            const void* __restrict__ bb,
                                            ushort_t* __restrict__ Y,
                                            const int* __restrict__ flagX,
                                            const int* __restrict__ flagP) {
  int isfx = flagX[0], isfp = flagP[0];
  int wave = threadIdx.x >> 6, lane = threadIdx.x & 63;
  size_t row = (size_t)blockIdx.x * 4 + wave;
  float v[8], s = 0.f, s2 = 0.f;
#pragma unroll
  for (int i = 0; i < 8; i++) {
    float x = loadx(X, row * C_ + lane + 64 * i, isfx);
    v[i] = x; s += x; s2 += x * x;
  }
#pragma unroll
  for (int off = 32; off >= 1; off >>= 1) {
    s += __shfl_xor(s, off); s2 += __shfl_xor(s2, off);
  }
  float mu = s * (1.0f / C_);
  float var = s2 * (1.0f / C_) - mu * mu;
  float rs = rsqrtf(var + 1e-5f);
  ushort_t* yr = Y + row * C_;
#pragma unroll
  for (int i = 0; i < 8; i++) {
    int c = lane + 64 * i;
    yr[c] = f2b((v[i] - mu) * rs * loadx(g, c, isfp) + loadx(bb, c, isfp));
  }
}

// ---- GEMM: Out[M,N] = A[M,K] (bf16) * B[K,N] (raw dtype), fp32 acc -------
// B transposed into LDS during staging. 64x64 tile, BK=64, 4 waves 2x2 frags.
// outF32: store fp32 into Out (fp32 container), else bf16.
// residual (fp32) read per output element if non-null.
__global__ __launch_bounds__(256) void gemm_n(const ushort_t* __restrict__ A,
                                              const void* __restrict__ Braw,
                                              int ldB, long bStrideZ,
                                              void* Out, int outF32,
                                              int K, int ldOut,
                                              const void* __restrict__ bias,
                                              int relu,
                                              const float* residual,
                                              const int* __restrict__ flag) {
  __shared__ __align__(16) ushort_t As[64 * 72];
  __shared__ __align__(16) ushort_t Bs[64 * 72];
  const int isf = flag[0];
  const int tid = threadIdx.x;
  const int lane = tid & 63, wave = tid >> 6;
  const int col_block = blockIdx.x + gridDim.x * blockIdx.z;
  const long row0 = (long)blockIdx.y * 64;
  const long col0 = (long)col_block * 64;      // Out columns
  const long col0b = (long)blockIdx.x * 64;    // B columns (within z-slice)
  const size_t zoff = (size_t)blockIdx.z * (size_t)bStrideZ;
  const ushort_t* Ab = A + (size_t)row0 * K;
  const int lrow = tid >> 2;          // 0..63
  const int lk = (tid & 3) * 16;      // 0,16,32,48
  const int wm = (wave >> 1) * 32, wn = (wave & 1) * 32;
  const int fq = lane >> 4, fl = lane & 15;
  floatx4 acc[2][2] = {};

  for (int k0 = 0; k0 < K; k0 += 64) {
    short8 a0 = *(const short8*)(Ab + (size_t)lrow * K + k0 + lk);
    short8 a1 = *(const short8*)(Ab + (size_t)lrow * K + k0 + lk + 8);
    float bvals[16];
#pragma unroll
    for (int i = 0; i < 16; i++)
      bvals[i] = loadx(Braw, zoff + (size_t)(k0 + lrow) * ldB + col0b + lk + i, isf);
    __syncthreads();
    *(short8*)&As[lrow * 72 + lk] = a0;
    *(short8*)&As[lrow * 72 + lk + 8] = a1;
#pragma unroll
    for (int i = 0; i < 16; i++)
      Bs[(lk + i) * 72 + lrow] = f2b(bvals[i]);   // Bs[n][k] = B[k][n]
    __syncthreads();
#pragma unroll
    for (int ks = 0; ks < 2; ks++) {
      short8 af0 = *(const short8*)&As[(wm + fl) * 72 + ks * 32 + fq * 8];
      short8 af1 = *(const short8*)&As[(wm + 16 + fl) * 72 + ks * 32 + fq * 8];
      short8 bf0 = *(const short8*)&Bs[(wn + fl) * 72 + ks * 32 + fq * 8];
      short8 bf1 = *(const short8*)&Bs[(wn + 16 + fl) * 72 + ks * 32 + fq * 8];
      acc[0][0] = __builtin_amdgcn_mfma_f32_16x16x32_bf16(af0, bf0, acc[0][0], 0, 0, 0);
      acc[0][1] = __builtin_amdgcn_mfma_f32_16x16x32_bf16(af0, bf1, acc[0][1], 0, 0, 0);
      acc[1][0] = __builtin_amdgcn_mfma_f32_16x16x32_bf16(af1, bf0, acc[1][0], 0, 0, 0);
      acc[1][1] = __builtin_amdgcn_mfma_f32_16x16x32_bf16(af1, bf1, acc[1][1], 0, 0, 0);
    }
  }
#pragma unroll
  for (int fm = 0; fm < 2; fm++)
#pragma unroll
    for (int fn = 0; fn < 2; fn++)
#pragma unroll
      for (int r = 0; r < 4; r++) {
        long grow = row0 + wm + fm * 16 + fq * 4 + r;   // C/D: row=quad*4+reg
        long gcol = col0 + wn + fn * 16 + fl;           // C/D: col=lane&15
        float v = acc[fm][fn][r];
        if (bias) v += loadx(bias, (size_t)(col0b + wn + fn * 16 + fl), isf);
        if (relu) v = fmaxf(v, 0.0f);
        size_t oi = (size_t)grow * ldOut + gcol;
        if (residual) v += residual[oi];
        if (outF32) ((float*)Out)[oi] = v;
        else        ((ushort_t*)Out)[oi] = f2b(v);
      }
}

// ---- flash attention + residual: X1 = X + softmax(QK^T*scale)V  (X1 fp32) -
__global__ __launch_bounds__(256) void flash_attn(const ushort_t* __restrict__ Q,
                                                  const ushort_t* __restrict__ Kx,
                                                  const ushort_t* __restrict__ V,
                                                  const void* __restrict__ X,
                                                  float* __restrict__ X1,
                                                  const int* __restrict__ flag) {
  __shared__ __align__(16) ushort_t kt[64 * 72];  // [s][d]
  __shared__ __align__(16) ushort_t vt[64 * 72];  // [d][s]
  __shared__ __align__(16) ushort_t pt[64 * 72];  // [q][s]
  const int isf = flag[0];
  const int tid = threadIdx.x;
  const int lane = tid & 63, wave = tid >> 6;
  const int fq = lane >> 4, fl = lane & 15;
  const int qtiles = T_ / 64;
  int qt_idx = blockIdx.x % qtiles;
  int bh = blockIdx.x / qtiles;
  int h = bh % H_, b = bh / H_;
  const size_t base = ((size_t)b * T_) * C_ + h * HS_;
  const int q0 = qt_idx * 64;

  short8 qf0, qf1;
  {
    const ushort_t* qp = Q + base + (size_t)(q0 + wave * 16 + fl) * C_ + fq * 8;
    qf0 = *(const short8*)(qp);
    qf1 = *(const short8*)(qp + 32);
  }
  float m[4] = {NEG_BIG, NEG_BIG, NEG_BIG, NEG_BIG};
  float l[4] = {0.f, 0.f, 0.f, 0.f};
  floatx4 oacc[4] = {};

  const int srow = tid >> 2;
  const int sd0 = (tid & 3) * 16;

  for (int st = 0; st <= qt_idx; st++) {
    int s0 = st * 64;
    short8 kv0 = *(const short8*)(Kx + base + (size_t)(s0 + srow) * C_ + sd0);
    short8 kv1 = *(const short8*)(Kx + base + (size_t)(s0 + srow) * C_ + sd0 + 8);
    short8 vv0 = *(const short8*)(V + base + (size_t)(s0 + srow) * C_ + sd0);
    short8 vv1 = *(const short8*)(V + base + (size_t)(s0 + srow) * C_ + sd0 + 8);
    __syncthreads();
    *(short8*)&kt[srow * 72 + sd0] = kv0;
    *(short8*)&kt[srow * 72 + sd0 + 8] = kv1;
#pragma unroll
    for (int i = 0; i < 8; i++) {
      vt[(sd0 + i) * 72 + srow] = (ushort_t)vv0[i];
      vt[(sd0 + 8 + i) * 72 + srow] = (ushort_t)vv1[i];
    }
    __syncthreads();

    floatx4 sacc[4] = {};
#pragma unroll
    for (int fn = 0; fn < 4; fn++) {
      short8 kf0 = *(const short8*)&kt[(fn * 16 + fl) * 72 + fq * 8];
      short8 kf1 = *(const short8*)&kt[(fn * 16 + fl) * 72 + 32 + fq * 8];
      sacc[fn] = __builtin_amdgcn_mfma_f32_16x16x32_bf16(qf0, kf0, sacc[fn], 0, 0, 0);
      sacc[fn] = __builtin_amdgcn_mfma_f32_16x16x32_bf16(qf1, kf1, sacc[fn], 0, 0, 0);
    }
    bool diag = (st == qt_idx);
    float p[4][4];
#pragma unroll
    for (int r = 0; r < 4; r++) {
      int qg = q0 + wave * 16 + fq * 4 + r;
      float rowmax = NEG_BIG;
#pragma unroll
      for (int fn = 0; fn < 4; fn++) {
        float s = sacc[fn][r] * SCALE;
        if (diag && (s0 + fn * 16 + fl) > qg) s = NEG_BIG;
        p[fn][r] = s;
        rowmax = fmaxf(rowmax, s);
      }
#pragma unroll
      for (int off = 8; off >= 1; off >>= 1)
        rowmax = fmaxf(rowmax, __shfl_xor(rowmax, off));
      float mn = fmaxf(m[r], rowmax);
      float alpha = __expf(m[r] - mn);
      m[r] = mn;
      float rsum = 0.f;
#pragma unroll
      for (int fn = 0; fn < 4; fn++) {
        float e = __expf(p[fn][r] - mn);
        p[fn][r] = e;
        rsum += e;
      }
#pragma unroll
      for (int off = 8; off >= 1; off >>= 1)
        rsum += __shfl_xor(rsum, off);
      l[r] = l[r] * alpha + rsum;
#pragma unroll
      for (int fn = 0; fn < 4; fn++) oacc[fn][r] *= alpha;
    }
#pragma unroll
    for (int fn = 0; fn < 4; fn++)
#pragma unroll
      for (int r = 0; r < 4; r++)
        pt[(wave * 16 + fq * 4 + r) * 72 + fn * 16 + fl] = f2b(p[fn][r]);
    __syncthreads();
    short8 pf0 = *(const short8*)&pt[(wave * 16 + fl) * 72 + fq * 8];
    short8 pf1 = *(const short8*)&pt[(wave * 16 + fl) * 72 + 32 + fq * 8];
#pragma unroll
    for (int fn = 0; fn < 4; fn++) {
      short8 vf0 = *(const short8*)&vt[(fn * 16 + fl) * 72 + fq * 8];
      short8 vf1 = *(const short8*)&vt[(fn * 16 + fl) * 72 + 32 + fq * 8];
      oacc[fn] = __builtin_amdgcn_mfma_f32_16x16x32_bf16(pf0, vf0, oacc[fn], 0, 0, 0);
      oacc[fn] = __builtin_amdgcn_mfma_f32_16x16x32_bf16(pf1, vf1, oacc[fn], 0, 0, 0);
    }
  }
#pragma unroll
  for (int fn = 0; fn < 4; fn++)
#pragma unroll
    for (int r = 0; r < 4; r++) {
      int qg = q0 + wave * 16 + fq * 4 + r;
      int d = fn * 16 + fl;
      size_t oi = base + (size_t)qg * C_ + d;
      X1[oi] = oacc[fn][r] / l[r] + loadx(X, oi, isf);   // fp32 store
    }
}

extern "C" void kernel_launch(void* const* d_in, const int* in_sizes, int n_in,
                              void* d_out, int out_size, void* d_ws, size_t ws_size,
                              hipStream_t stream) {
  const void* x  = d_in[0];
  const void* wq = d_in[1];
  const void* wk = d_in[2];
  const void* wv = d_in[3];
  const void* w1 = d_in[4];
  const void* b1 = d_in[5];
  const void* w2 = d_in[6];
  const void* b2 = d_in[7];
  const void* ln1g = d_in[8];
  const void* ln1b = d_in[9];
  const void* ln2g = d_in[10];
  const void* ln2b = d_in[11];
  ushort_t* ws = (ushort_t*)d_ws;

  const size_t SZ = (size_t)M_ * C_;   // 4,194,304 elems
  // ws layout (high-water 4*SZ*2B + 16 B = 16.8 MB):
  //   h [0,SZ) | q [SZ,2SZ) | k [2SZ,3SZ) | v [3SZ,4SZ) | flag @4SZ
  //   h2 reuses h (dead after QKV); ff1 reuses q..v (2SZ per half pass)
  ushort_t* h   = ws;
  ushort_t* q   = ws + SZ;
  ushort_t* k   = ws + 2 * SZ;
  ushort_t* v   = ws + 3 * SZ;
  ushort_t* ff1 = ws + SZ;              // [SZ,3SZ): 4096x2048 bf16 per pass
  ushort_t* h2  = h;
  int* flag     = (int*)(ws + 4 * SZ);  // [0]=inputs-fp32?, [1]=1
  float* x1     = (float*)d_out;        // fp32 residual-1, lives in d_out
  float* outf   = (float*)d_out;        // final output, fp32

  detect_k<<<1, 256, 0, stream>>>((const ushort_t*)x, flag);

  // LN1: raw x -> h (bf16, ws)
  ln_k<<<M_ / 4, 256, 0, stream>>>(x, ln1g, ln1b, h, flag, flag);
  // QKV: A=h, B=raw per-head weights [512,64], z=head; bf16 out
  gemm_n<<<dim3(1, 128, 8), 256, 0, stream>>>(h, wq, 64, (long)C_ * HS_, q, 0,
                                              512, 512, nullptr, 0, nullptr, flag);
  gemm_n<<<dim3(1, 128, 8), 256, 0, stream>>>(h, wk, 64, (long)C_ * HS_, k, 0,
                                              512, 512, nullptr, 0, nullptr, flag);
  gemm_n<<<dim3(1, 128, 8), 256, 0, stream>>>(h, wv, 64, (long)C_ * HS_, v, 0,
                                              512, 512, nullptr, 0, nullptr, flag);
  // attention + residual(raw x) -> x1 (fp32, d_out)
  flash_attn<<<B_ * H_ * (T_ / 64), 256, 0, stream>>>(q, k, v, x, x1, flag);
  // LN2: x1 (fp32 -> flag[1]=1) -> h2 (bf16)
  ln_k<<<M_ / 4, 256, 0, stream>>>((const void*)x1, ln2g, ln2b, h2, flag + 1, flag);
  // FFN in two half-row passes; ff1 bf16 in q..v slots
  for (int p = 0; p < 2; p++) {
    const size_t roff = (size_t)p * 4096;
    gemm_n<<<dim3(32, 64, 1), 256, 0, stream>>>(h2 + roff * C_, w1, 2048, 0, ff1, 0,
                                                512, 2048, b1, 1, nullptr, flag);
    gemm_n<<<dim3(8, 64, 1), 256, 0, stream>>>(ff1, w2, 512, 0, outf + roff * C_, 1,
                                               2048, 512, b2, 0, x1 + roff * C_, flag);
  }
}

// Round 6
// 438.051 us; speedup vs baseline: 2.2676x; 2.2676x over previous
//
#include <hip/hip_runtime.h>

typedef unsigned short ushort_t;
typedef __attribute__((ext_vector_type(8))) short short8;   // 8 bf16 (4 VGPRs)
typedef __attribute__((ext_vector_type(4))) float floatx4;  // 4 fp32 acc

#define B_  4
#define T_  2048
#define C_  512
#define H_  8
#define HS_ 64
#define M_  (B_*T_)          // 8192 rows
#define SCALE 0.04419417382415922f  // 512^-0.5
#define NEG_BIG (-3.0e4f)

__device__ __forceinline__ float b2f(ushort_t u) {
  union { unsigned int i; float f; } w; w.i = ((unsigned int)u) << 16; return w.f;
}
__device__ __forceinline__ ushort_t f2b(float f) {
  union { float f; unsigned int i; } w; w.f = f;
  unsigned int x = w.i;
  return (ushort_t)((x + 0x7fffu + ((x >> 16) & 1u)) >> 16);  // RNE
}
__device__ __forceinline__ float loadx(const void* p, size_t i, int isf32) {
  return isf32 ? ((const float*)p)[i] : b2f(((const ushort_t*)p)[i]);
}

// ---- input dtype detector: flag[0]=1 iff inputs are fp32 containers ------
__global__ void detect_k(const ushort_t* __restrict__ xraw,
                         int* __restrict__ flag) {
  __shared__ int bad, lowzero;
  if (threadIdx.x == 0) { bad = 0; lowzero = 0; }
  __syncthreads();
  int b = 0, z = 0;
  for (int i = threadIdx.x; i < 16384; i += 256) {
    ushort_t u = xraw[i];
    if (((u >> 7) & 0xFF) == 0xFF) b++;
    if (((i & 1) == 0) && (u == 0)) z++;
  }
  atomicAdd(&bad, b); atomicAdd(&lowzero, z);
  __syncthreads();
  if (threadIdx.x == 0) {
    flag[0] = (bad > 0 || lowzero > 6000) ? 1 : 0;
    flag[1] = 1;
  }
}

// ---- convert + transpose: out[n][k] = bf16(in[k][n]), batched over z -----
__global__ __launch_bounds__(256) void transpose_k(const void* __restrict__ in,
                                                   ushort_t* __restrict__ out,
                                                   int K, int N,
                                                   const int* __restrict__ flag) {
  __shared__ ushort_t t[32][33];
  int isf = flag[0];
  size_t zoff = (size_t)blockIdx.z * K * N;
  out += zoff;
  int n0 = blockIdx.x * 32, k0 = blockIdx.y * 32;
  int tx = threadIdx.x & 31, ty = threadIdx.x >> 5;
#pragma unroll
  for (int i = 0; i < 4; i++)
    t[ty + 8 * i][tx] = f2b(loadx(in, zoff + (size_t)(k0 + ty + 8 * i) * N + n0 + tx, isf));
  __syncthreads();
#pragma unroll
  for (int i = 0; i < 4; i++)
    out[(size_t)(n0 + ty + 8 * i) * K + k0 + tx] = t[tx][ty + 8 * i];
}

// ---- LayerNorm: wave per row of 512 --------------------------------------
__global__ __launch_bounds__(256) void ln_k(const void* __restrict__ X,
                                            const void* __restrict__ g,
                                            const void* __restrict__ bb,
                                            ushort_t* __restrict__ Y,
                                            const int* __restrict__ flagX,
                                            const int* __restrict__ flagP) {
  int isfx = flagX[0], isfp = flagP[0];
  int wave = threadIdx.x >> 6, lane = threadIdx.x & 63;
  size_t row = (size_t)blockIdx.x * 4 + wave;
  float v[8], s = 0.f, s2 = 0.f;
#pragma unroll
  for (int i = 0; i < 8; i++) {
    float x = loadx(X, row * C_ + lane + 64 * i, isfx);
    v[i] = x; s += x; s2 += x * x;
  }
#pragma unroll
  for (int off = 32; off >= 1; off >>= 1) {
    s += __shfl_xor(s, off); s2 += __shfl_xor(s2, off);
  }
  float mu = s * (1.0f / C_);
  float var = s2 * (1.0f / C_) - mu * mu;
  float rs = rsqrtf(var + 1e-5f);
  ushort_t* yr = Y + row * C_;
#pragma unroll
  for (int i = 0; i < 8; i++) {
    int c = lane + 64 * i;
    yr[c] = f2b((v[i] - mu) * rs * loadx(g, c, isfp) + loadx(bb, c, isfp));
  }
}

// ---- GEMM 128x128: Out[M,N] = A[M,K](bf16) * Bt[N,K]^T(bf16), fp32 acc ---
// BK=64, 4 waves each 64x64 (4x4 frags of 16x16x32). m93-style.
__global__ __launch_bounds__(256) void gemm_bt128(const ushort_t* __restrict__ A,
                                                  const ushort_t* __restrict__ Bt,
                                                  void* Out, int outF32,
                                                  int K, int ldOut,
                                                  const void* __restrict__ bias,
                                                  int relu,
                                                  const float* residual,
                                                  const int* __restrict__ flag) {
  __shared__ __align__(16) ushort_t As[128 * 72];
  __shared__ __align__(16) ushort_t Bs[128 * 72];
  const int isf = flag[0];
  const int tid = threadIdx.x;
  const int lane = tid & 63, wave = tid >> 6;
  const long row0 = (long)blockIdx.y * 128;
  const long col0 = (long)blockIdx.x * 128;
  const ushort_t* Ab = A + (size_t)row0 * K;
  const ushort_t* Bb = Bt + (size_t)col0 * K;
  const int sr = tid >> 1;           // 0..127 staging row
  const int sk = (tid & 1) * 32;     // 0 or 32
  const int wm = (wave >> 1) * 64, wn = (wave & 1) * 64;
  const int fq = lane >> 4, fl = lane & 15;
  floatx4 acc[4][4] = {};

  for (int k0 = 0; k0 < K; k0 += 64) {
    short8 a0 = *(const short8*)(Ab + (size_t)sr * K + k0 + sk);
    short8 a1 = *(const short8*)(Ab + (size_t)sr * K + k0 + sk + 8);
    short8 a2 = *(const short8*)(Ab + (size_t)sr * K + k0 + sk + 16);
    short8 a3 = *(const short8*)(Ab + (size_t)sr * K + k0 + sk + 24);
    short8 b0 = *(const short8*)(Bb + (size_t)sr * K + k0 + sk);
    short8 b1 = *(const short8*)(Bb + (size_t)sr * K + k0 + sk + 8);
    short8 b2 = *(const short8*)(Bb + (size_t)sr * K + k0 + sk + 16);
    short8 b3 = *(const short8*)(Bb + (size_t)sr * K + k0 + sk + 24);
    __syncthreads();
    *(short8*)&As[sr * 72 + sk]      = a0;
    *(short8*)&As[sr * 72 + sk + 8]  = a1;
    *(short8*)&As[sr * 72 + sk + 16] = a2;
    *(short8*)&As[sr * 72 + sk + 24] = a3;
    *(short8*)&Bs[sr * 72 + sk]      = b0;
    *(short8*)&Bs[sr * 72 + sk + 8]  = b1;
    *(short8*)&Bs[sr * 72 + sk + 16] = b2;
    *(short8*)&Bs[sr * 72 + sk + 24] = b3;
    __syncthreads();
#pragma unroll
    for (int ks = 0; ks < 2; ks++) {
      short8 af[4], bf[4];
#pragma unroll
      for (int i = 0; i < 4; i++) {
        af[i] = *(const short8*)&As[(wm + i * 16 + fl) * 72 + ks * 32 + fq * 8];
        bf[i] = *(const short8*)&Bs[(wn + i * 16 + fl) * 72 + ks * 32 + fq * 8];
      }
#pragma unroll
      for (int fi = 0; fi < 4; fi++)
#pragma unroll
        for (int fj = 0; fj < 4; fj++)
          acc[fi][fj] = __builtin_amdgcn_mfma_f32_16x16x32_bf16(af[fi], bf[fj], acc[fi][fj], 0, 0, 0);
    }
  }
#pragma unroll
  for (int fi = 0; fi < 4; fi++)
#pragma unroll
    for (int fj = 0; fj < 4; fj++) {
      long gcol = col0 + wn + fj * 16 + fl;           // C/D: col=lane&15
      float bv = bias ? loadx(bias, (size_t)gcol, isf) : 0.0f;
#pragma unroll
      for (int r = 0; r < 4; r++) {
        long grow = row0 + wm + fi * 16 + fq * 4 + r; // C/D: row=quad*4+reg
        float v = acc[fi][fj][r] + bv;
        if (relu) v = fmaxf(v, 0.0f);
        size_t oi = (size_t)grow * ldOut + gcol;
        if (residual) v += residual[oi];
        if (outF32) ((float*)Out)[oi] = v;
        else        ((ushort_t*)Out)[oi] = f2b(v);
      }
    }
}

// ---- flash attention + residual, paired q-tiles for load balance ---------
// block = (b, h, pair p) handling q-tiles {31-p, p}: uniform 33 s-tile steps
__global__ __launch_bounds__(256) void flash_attn(const ushort_t* __restrict__ Q,
                                                  const ushort_t* __restrict__ Kx,
                                                  const ushort_t* __restrict__ V,
                                                  const void* __restrict__ X,
                                                  float* __restrict__ X1,
                                                  const int* __restrict__ flag) {
  __shared__ __align__(16) ushort_t kt[64 * 72];  // [s][d]
  __shared__ __align__(16) ushort_t vt[64 * 72];  // [d][s]
  __shared__ __align__(16) ushort_t pt[64 * 72];  // [q][s]
  const int isf = flag[0];
  const int tid = threadIdx.x;
  const int lane = tid & 63, wave = tid >> 6;
  const int fq = lane >> 4, fl = lane & 15;
  const int qtiles = T_ / 64;                 // 32
  const int npairs = qtiles / 2;              // 16
  int pairI = blockIdx.x % npairs;
  int bh = blockIdx.x / npairs;
  int h = bh % H_, b = bh / H_;
  const size_t base = ((size_t)b * T_) * C_ + h * HS_;
  const int srow = tid >> 2;
  const int sd0 = (tid & 3) * 16;

  for (int half = 0; half < 2; half++) {
    const int qt_idx = half == 0 ? (qtiles - 1 - pairI) : pairI;  // heavy first
    const int q0 = qt_idx * 64;

    short8 qf0, qf1;
    {
      const ushort_t* qp = Q + base + (size_t)(q0 + wave * 16 + fl) * C_ + fq * 8;
      qf0 = *(const short8*)(qp);
      qf1 = *(const short8*)(qp + 32);
    }
    float m[4] = {NEG_BIG, NEG_BIG, NEG_BIG, NEG_BIG};
    float l[4] = {0.f, 0.f, 0.f, 0.f};
    floatx4 oacc[4] = {};

    for (int st = 0; st <= qt_idx; st++) {
      int s0 = st * 64;
      short8 kv0 = *(const short8*)(Kx + base + (size_t)(s0 + srow) * C_ + sd0);
      short8 kv1 = *(const short8*)(Kx + base + (size_t)(s0 + srow) * C_ + sd0 + 8);
      short8 vv0 = *(const short8*)(V + base + (size_t)(s0 + srow) * C_ + sd0);
      short8 vv1 = *(const short8*)(V + base + (size_t)(s0 + srow) * C_ + sd0 + 8);
      __syncthreads();
      *(short8*)&kt[srow * 72 + sd0] = kv0;
      *(short8*)&kt[srow * 72 + sd0 + 8] = kv1;
#pragma unroll
      for (int i = 0; i < 8; i++) {
        vt[(sd0 + i) * 72 + srow] = (ushort_t)vv0[i];
        vt[(sd0 + 8 + i) * 72 + srow] = (ushort_t)vv1[i];
      }
      __syncthreads();

      floatx4 sacc[4] = {};
#pragma unroll
      for (int fn = 0; fn < 4; fn++) {
        short8 kf0 = *(const short8*)&kt[(fn * 16 + fl) * 72 + fq * 8];
        short8 kf1 = *(const short8*)&kt[(fn * 16 + fl) * 72 + 32 + fq * 8];
        sacc[fn] = __builtin_amdgcn_mfma_f32_16x16x32_bf16(qf0, kf0, sacc[fn], 0, 0, 0);
        sacc[fn] = __builtin_amdgcn_mfma_f32_16x16x32_bf16(qf1, kf1, sacc[fn], 0, 0, 0);
      }
      bool diag = (st == qt_idx);
      float p[4][4];
#pragma unroll
      for (int r = 0; r < 4; r++) {
        int qg = q0 + wave * 16 + fq * 4 + r;
        float rowmax = NEG_BIG;
#pragma unroll
        for (int fn = 0; fn < 4; fn++) {
          float s = sacc[fn][r] * SCALE;
          if (diag && (s0 + fn * 16 + fl) > qg) s = NEG_BIG;
          p[fn][r] = s;
          rowmax = fmaxf(rowmax, s);
        }
#pragma unroll
        for (int off = 8; off >= 1; off >>= 1)
          rowmax = fmaxf(rowmax, __shfl_xor(rowmax, off));
        float mn = fmaxf(m[r], rowmax);
        float alpha = __expf(m[r] - mn);
        m[r] = mn;
        float rsum = 0.f;
#pragma unroll
        for (int fn = 0; fn < 4; fn++) {
          float e = __expf(p[fn][r] - mn);
          p[fn][r] = e;
          rsum += e;
        }
#pragma unroll
        for (int off = 8; off >= 1; off >>= 1)
          rsum += __shfl_xor(rsum, off);
        l[r] = l[r] * alpha + rsum;
#pragma unroll
        for (int fn = 0; fn < 4; fn++) oacc[fn][r] *= alpha;
      }
#pragma unroll
      for (int fn = 0; fn < 4; fn++)
#pragma unroll
        for (int r = 0; r < 4; r++)
          pt[(wave * 16 + fq * 4 + r) * 72 + fn * 16 + fl] = f2b(p[fn][r]);
      __syncthreads();
      short8 pf0 = *(const short8*)&pt[(wave * 16 + fl) * 72 + fq * 8];
      short8 pf1 = *(const short8*)&pt[(wave * 16 + fl) * 72 + 32 + fq * 8];
#pragma unroll
      for (int fn = 0; fn < 4; fn++) {
        short8 vf0 = *(const short8*)&vt[(fn * 16 + fl) * 72 + fq * 8];
        short8 vf1 = *(const short8*)&vt[(fn * 16 + fl) * 72 + 32 + fq * 8];
        oacc[fn] = __builtin_amdgcn_mfma_f32_16x16x32_bf16(pf0, vf0, oacc[fn], 0, 0, 0);
        oacc[fn] = __builtin_amdgcn_mfma_f32_16x16x32_bf16(pf1, vf1, oacc[fn], 0, 0, 0);
      }
    }
#pragma unroll
    for (int fn = 0; fn < 4; fn++)
#pragma unroll
      for (int r = 0; r < 4; r++) {
        int qg = q0 + wave * 16 + fq * 4 + r;
        int d = fn * 16 + fl;
        size_t oi = base + (size_t)qg * C_ + d;
        X1[oi] = oacc[fn][r] / l[r] + loadx(X, oi, isf);
      }
  }
}

extern "C" void kernel_launch(void* const* d_in, const int* in_sizes, int n_in,
                              void* d_out, int out_size, void* d_ws, size_t ws_size,
                              hipStream_t stream) {
  const void* x  = d_in[0];
  const void* wq = d_in[1];
  const void* wk = d_in[2];
  const void* wv = d_in[3];
  const void* w1 = d_in[4];
  const void* b1 = d_in[5];
  const void* w2 = d_in[6];
  const void* b2 = d_in[7];
  const void* ln1g = d_in[8];
  const void* ln1b = d_in[9];
  const void* ln2g = d_in[10];
  const void* ln2b = d_in[11];
  ushort_t* ws = (ushort_t*)d_ws;

  const size_t SZ = (size_t)M_ * C_;   // 4,194,304 elems
  // ws layout (high-water 39.3 MB — proven in-bounds by R3≡R4 evidence):
  //   h [0,SZ) | q [SZ,2SZ) | k [2SZ,3SZ) | v [3SZ,4SZ)
  //   qkvt [4SZ, +786432) | w1t +1048576 | w2t +1048576 | flag
  //   ff1 reuses q..v (2SZ per half-row pass); h2 reuses h
  ushort_t* h    = ws;
  ushort_t* q    = ws + SZ;
  ushort_t* k    = ws + 2 * SZ;
  ushort_t* v    = ws + 3 * SZ;
  ushort_t* ff1  = ws + SZ;
  ushort_t* qkvt = ws + 4 * SZ;
  ushort_t* w1t  = qkvt + 3 * (size_t)H_ * HS_ * C_;
  ushort_t* w2t  = w1t + (size_t)4 * C_ * C_;
  int* flag      = (int*)(w2t + (size_t)4 * C_ * C_);
  ushort_t* h2   = h;
  float* x1      = (float*)d_out;
  float* outf    = (float*)d_out;

  detect_k<<<1, 256, 0, stream>>>((const ushort_t*)x, flag);

  // convert+transpose weights to bf16 [N][K]
  transpose_k<<<dim3(2, 16, 8), 256, 0, stream>>>(wq, qkvt, 512, 64, flag);
  transpose_k<<<dim3(2, 16, 8), 256, 0, stream>>>(wk, qkvt + (size_t)H_ * HS_ * C_, 512, 64, flag);
  transpose_k<<<dim3(2, 16, 8), 256, 0, stream>>>(wv, qkvt + 2 * (size_t)H_ * HS_ * C_, 512, 64, flag);
  transpose_k<<<dim3(64, 16, 1), 256, 0, stream>>>(w1, w1t, 512, 2048, flag);
  transpose_k<<<dim3(16, 64, 1), 256, 0, stream>>>(w2, w2t, 2048, 512, flag);

  // LN1: raw x -> h (bf16)
  ln_k<<<M_ / 4, 256, 0, stream>>>(x, ln1g, ln1b, h, flag, flag);
  // QKV projections: M=8192, N=512, K=512
  gemm_bt128<<<dim3(4, 64), 256, 0, stream>>>(h, qkvt, q, 0, 512, 512,
                                              nullptr, 0, nullptr, flag);
  gemm_bt128<<<dim3(4, 64), 256, 0, stream>>>(h, qkvt + (size_t)H_ * HS_ * C_, k, 0, 512, 512,
                                              nullptr, 0, nullptr, flag);
  gemm_bt128<<<dim3(4, 64), 256, 0, stream>>>(h, qkvt + 2 * (size_t)H_ * HS_ * C_, v, 0, 512, 512,
                                              nullptr, 0, nullptr, flag);
  // attention + residual(raw x) -> x1 (fp32, d_out); paired q-tiles
  flash_attn<<<B_ * H_ * (T_ / 128), 256, 0, stream>>>(q, k, v, x, x1, flag);
  // LN2: x1 (fp32) -> h2 (bf16)
  ln_k<<<M_ / 4, 256, 0, stream>>>((const void*)x1, ln2g, ln2b, h2, flag + 1, flag);
  // FFN in two half-row passes (M=4096 each)
  for (int p = 0; p < 2; p++) {
    const size_t roff = (size_t)p * 4096;
    gemm_bt128<<<dim3(16, 32), 256, 0, stream>>>(h2 + roff * C_, w1t, ff1, 0, 512, 2048,
                                                 b1, 1, nullptr, flag);
    gemm_bt128<<<dim3(4, 32), 256, 0, stream>>>(ff1, w2t, outf + roff * C_, 1, 2048, 512,
                                                b2, 0, x1 + roff * C_, flag);
  }
}

// Round 7
// 359.658 us; speedup vs baseline: 2.7619x; 1.2180x over previous
//
#include <hip/hip_runtime.h>

typedef unsigned short ushort_t;
typedef __attribute__((ext_vector_type(8))) short short8;   // 8 bf16 (4 VGPRs)
typedef __attribute__((ext_vector_type(4))) float floatx4;  // 4 fp32 acc

#define B_  4
#define T_  2048
#define C_  512
#define H_  8
#define HS_ 64
#define M_  (B_*T_)          // 8192 rows
#define SCALE 0.04419417382415922f  // 512^-0.5
#define NEG_BIG (-3.0e4f)

__device__ __forceinline__ float b2f(ushort_t u) {
  union { unsigned int i; float f; } w; w.i = ((unsigned int)u) << 16; return w.f;
}
__device__ __forceinline__ ushort_t f2b(float f) {
  union { float f; unsigned int i; } w; w.f = f;
  unsigned int x = w.i;
  return (ushort_t)((x + 0x7fffu + ((x >> 16) & 1u)) >> 16);  // RNE
}

// ---- convert + transpose: out[n][k] = bf16(in[k][n]), batched over z -----
__global__ __launch_bounds__(256) void transpose_k(const float* __restrict__ in,
                                                   ushort_t* __restrict__ out,
                                                   int K, int N) {
  __shared__ ushort_t t[32][33];
  size_t zoff = (size_t)blockIdx.z * K * N;
  int n0 = blockIdx.x * 32, k0 = blockIdx.y * 32;
  int tx = threadIdx.x & 31, ty = threadIdx.x >> 5;
#pragma unroll
  for (int i = 0; i < 4; i++)
    t[ty + 8 * i][tx] = f2b(in[zoff + (size_t)(k0 + ty + 8 * i) * N + n0 + tx]);
  __syncthreads();
#pragma unroll
  for (int i = 0; i < 4; i++)
    out[zoff + (size_t)(n0 + ty + 8 * i) * K + k0 + tx] = t[tx][ty + 8 * i];
}

// ---- LayerNorm: wave per row of 512 (fp32 in, bf16 out) ------------------
__global__ __launch_bounds__(256) void ln_k(const float* __restrict__ X,
                                            const float* __restrict__ g,
                                            const float* __restrict__ bb,
                                            ushort_t* __restrict__ Y) {
  int wave = threadIdx.x >> 6, lane = threadIdx.x & 63;
  size_t row = (size_t)blockIdx.x * 4 + wave;
  float v[8], s = 0.f, s2 = 0.f;
#pragma unroll
  for (int i = 0; i < 8; i++) {
    float x = X[row * C_ + lane + 64 * i];
    v[i] = x; s += x; s2 += x * x;
  }
#pragma unroll
  for (int off = 32; off >= 1; off >>= 1) {
    s += __shfl_xor(s, off); s2 += __shfl_xor(s2, off);
  }
  float mu = s * (1.0f / C_);
  float var = s2 * (1.0f / C_) - mu * mu;
  float rs = rsqrtf(var + 1e-5f);
  ushort_t* yr = Y + row * C_;
#pragma unroll
  for (int i = 0; i < 8; i++) {
    int c = lane + 64 * i;
    yr[c] = f2b((v[i] - mu) * rs * g[c] + bb[c]);
  }
}

// ---- out[i] += b2[i % 512]  (prepares FFN2 atomic accumulation) ----------
__global__ __launch_bounds__(256) void init_out_k(float* __restrict__ out,
                                                  const float* __restrict__ b2,
                                                  int n) {
  int i = blockIdx.x * 256 + threadIdx.x;
  if (i < n) out[i] += b2[i & (C_ - 1)];
}

// ---- GEMM 128x128: Out[M,N] = A[M,K](bf16) * Bt[N,K]^T(bf16), fp32 acc ---
// BK=64, 4 waves each 64x64 (4x4 frags of 16x16x32). m93-style.
// outMode: 0=bf16 store, 1=fp32 store, 2=fp32 atomicAdd (K-split partials;
// bias/relu ignored). kOff = blockIdx.z * kLen.
__global__ __launch_bounds__(256) void gemm_bt128(const ushort_t* __restrict__ A,
                                                  const ushort_t* __restrict__ Bt,
                                                  void* Out, int outMode,
                                                  int K, int kLen, int ldOut,
                                                  const float* __restrict__ bias,
                                                  int relu) {
  __shared__ __align__(16) ushort_t As[128 * 72];
  __shared__ __align__(16) ushort_t Bs[128 * 72];
  const int tid = threadIdx.x;
  const int lane = tid & 63, wave = tid >> 6;
  const long row0 = (long)blockIdx.y * 128;
  const long col0 = (long)blockIdx.x * 128;
  const int kOff = blockIdx.z * kLen;
  const ushort_t* Ab = A + (size_t)row0 * K;
  const ushort_t* Bb = Bt + (size_t)col0 * K;
  const int sr = tid >> 1;           // 0..127 staging row
  const int sk = (tid & 1) * 32;     // 0 or 32
  const int wm = (wave >> 1) * 64, wn = (wave & 1) * 64;
  const int fq = lane >> 4, fl = lane & 15;
  floatx4 acc[4][4] = {};

  for (int k0 = kOff; k0 < kOff + kLen; k0 += 64) {
    short8 a0 = *(const short8*)(Ab + (size_t)sr * K + k0 + sk);
    short8 a1 = *(const short8*)(Ab + (size_t)sr * K + k0 + sk + 8);
    short8 a2 = *(const short8*)(Ab + (size_t)sr * K + k0 + sk + 16);
    short8 a3 = *(const short8*)(Ab + (size_t)sr * K + k0 + sk + 24);
    short8 b0 = *(const short8*)(Bb + (size_t)sr * K + k0 + sk);
    short8 b1 = *(const short8*)(Bb + (size_t)sr * K + k0 + sk + 8);
    short8 b2 = *(const short8*)(Bb + (size_t)sr * K + k0 + sk + 16);
    short8 b3 = *(const short8*)(Bb + (size_t)sr * K + k0 + sk + 24);
    __syncthreads();
    *(short8*)&As[sr * 72 + sk]      = a0;
    *(short8*)&As[sr * 72 + sk + 8]  = a1;
    *(short8*)&As[sr * 72 + sk + 16] = a2;
    *(short8*)&As[sr * 72 + sk + 24] = a3;
    *(short8*)&Bs[sr * 72 + sk]      = b0;
    *(short8*)&Bs[sr * 72 + sk + 8]  = b1;
    *(short8*)&Bs[sr * 72 + sk + 16] = b2;
    *(short8*)&Bs[sr * 72 + sk + 24] = b3;
    __syncthreads();
#pragma unroll
    for (int ks = 0; ks < 2; ks++) {
      short8 af[4], bf[4];
#pragma unroll
      for (int i = 0; i < 4; i++) {
        af[i] = *(const short8*)&As[(wm + i * 16 + fl) * 72 + ks * 32 + fq * 8];
        bf[i] = *(const short8*)&Bs[(wn + i * 16 + fl) * 72 + ks * 32 + fq * 8];
      }
#pragma unroll
      for (int fi = 0; fi < 4; fi++)
#pragma unroll
        for (int fj = 0; fj < 4; fj++)
          acc[fi][fj] = __builtin_amdgcn_mfma_f32_16x16x32_bf16(af[fi], bf[fj], acc[fi][fj], 0, 0, 0);
    }
  }
#pragma unroll
  for (int fi = 0; fi < 4; fi++)
#pragma unroll
    for (int fj = 0; fj < 4; fj++) {
      long gcol = col0 + wn + fj * 16 + fl;           // C/D: col=lane&15
      float bv = bias ? bias[gcol] : 0.0f;
#pragma unroll
      for (int r = 0; r < 4; r++) {
        long grow = row0 + wm + fi * 16 + fq * 4 + r; // C/D: row=quad*4+reg
        size_t oi = (size_t)grow * ldOut + gcol;
        float v = acc[fi][fj][r];
        if (outMode == 2) {
          atomicAdd(&((float*)Out)[oi], v);
        } else {
          v += bv;
          if (relu) v = fmaxf(v, 0.0f);
          if (outMode == 1) ((float*)Out)[oi] = v;
          else              ((ushort_t*)Out)[oi] = f2b(v);
        }
      }
    }
}

// ---- flash attention + residual: X1 = X + softmax(QK^T*scale)V -----------
// QKV packed [M,1536] (Q|K|V each 512 cols, head-major 64). One 64-row
// q-tile per block; heavy tiles first (qt = 31 - blockIdx>>5) for LPT pack.
__global__ __launch_bounds__(256) void flash_attn(const ushort_t* __restrict__ QKV,
                                                  const float* __restrict__ X,
                                                  float* __restrict__ X1) {
  __shared__ __align__(16) ushort_t kt[64 * 72];  // [s][d]
  __shared__ __align__(16) ushort_t vt[64 * 72];  // [d][s^swz] (b32 writes)
  __shared__ __align__(16) ushort_t pt[64 * 72];  // [q][s]
  const int tid = threadIdx.x;
  const int lane = tid & 63, wave = tid >> 6;
  const int fq = lane >> 4, fl = lane & 15;
  const int qt_idx = (T_ / 64 - 1) - (blockIdx.x >> 5);  // 31..0, heavy first
  const int bh = blockIdx.x & 31;
  const int h = bh & 7, b = bh >> 3;
  const int hoff = h * HS_;
  const int q0 = qt_idx * 64;
  const int LD = 3 * C_;              // 1536

  short8 qf0, qf1;
  {
    const ushort_t* qp = QKV + (size_t)((size_t)b * T_ + q0 + wave * 16 + fl) * LD + hoff + fq * 8;
    qf0 = *(const short8*)(qp);
    qf1 = *(const short8*)(qp + 32);
  }
  float m[4] = {NEG_BIG, NEG_BIG, NEG_BIG, NEG_BIG};
  float l[4] = {0.f, 0.f, 0.f, 0.f};
  floatx4 oacc[4] = {};

  const int sr = (tid >> 3) * 2;      // 0,2,..,62
  const int d0 = (tid & 7) * 8;       // 0..56

  for (int st = 0; st <= qt_idx; st++) {
    int s0 = st * 64;
    const ushort_t* kp = QKV + (size_t)((size_t)b * T_ + s0 + sr) * LD + hoff + C_;
    short8 k0v = *(const short8*)(kp + d0);
    short8 k1v = *(const short8*)(kp + LD + d0);
    short8 v0v = *(const short8*)(kp + C_ + d0);
    short8 v1v = *(const short8*)(kp + C_ + LD + d0);
    __syncthreads();
    *(short8*)&kt[sr * 72 + d0] = k0v;
    *(short8*)&kt[(sr + 1) * 72 + d0] = k1v;
#pragma unroll
    for (int i = 0; i < 8; i++) {
      int d = d0 + i;
      int scol = sr ^ (8 * (d >> 3));   // XOR swizzle: 2-way max (free)
      unsigned int pk = ((unsigned int)(ushort_t)v0v[i]) |
                        (((unsigned int)(ushort_t)v1v[i]) << 16);
      *(unsigned int*)&vt[d * 72 + scol] = pk;
    }
    __syncthreads();

    // S = Q K^T
    floatx4 sacc[4] = {};
#pragma unroll
    for (int fn = 0; fn < 4; fn++) {
      short8 kf0 = *(const short8*)&kt[(fn * 16 + fl) * 72 + fq * 8];
      short8 kf1 = *(const short8*)&kt[(fn * 16 + fl) * 72 + 32 + fq * 8];
      sacc[fn] = __builtin_amdgcn_mfma_f32_16x16x32_bf16(qf0, kf0, sacc[fn], 0, 0, 0);
      sacc[fn] = __builtin_amdgcn_mfma_f32_16x16x32_bf16(qf1, kf1, sacc[fn], 0, 0, 0);
    }
    bool diag = (st == qt_idx);
    float p[4][4];
#pragma unroll
    for (int r = 0; r < 4; r++) {
      int qg = q0 + wave * 16 + fq * 4 + r;
      float rowmax = NEG_BIG;
#pragma unroll
      for (int fn = 0; fn < 4; fn++) {
        float s = sacc[fn][r] * SCALE;
        if (diag && (s0 + fn * 16 + fl) > qg) s = NEG_BIG;
        p[fn][r] = s;
        rowmax = fmaxf(rowmax, s);
      }
#pragma unroll
      for (int off = 8; off >= 1; off >>= 1)
        rowmax = fmaxf(rowmax, __shfl_xor(rowmax, off));
      float mn = fmaxf(m[r], rowmax);
      float alpha = __expf(m[r] - mn);
      m[r] = mn;
      float rsum = 0.f;
#pragma unroll
      for (int fn = 0; fn < 4; fn++) {
        float e = __expf(p[fn][r] - mn);
        p[fn][r] = e;
        rsum += e;
      }
#pragma unroll
      for (int off = 8; off >= 1; off >>= 1)
        rsum += __shfl_xor(rsum, off);
      l[r] = l[r] * alpha + rsum;
#pragma unroll
      for (int fn = 0; fn < 4; fn++) oacc[fn][r] *= alpha;
    }
    // P: C-layout -> LDS -> A-layout. Rows wave*16.. are per-wave-private:
    // no cross-wave sharing -> no barrier needed (compiler orders intra-wave).
#pragma unroll
    for (int fn = 0; fn < 4; fn++)
#pragma unroll
      for (int r = 0; r < 4; r++)
        pt[(wave * 16 + fq * 4 + r) * 72 + fn * 16 + fl] = f2b(p[fn][r]);
    short8 pf0 = *(const short8*)&pt[(wave * 16 + fl) * 72 + fq * 8];
    short8 pf1 = *(const short8*)&pt[(wave * 16 + fl) * 72 + 32 + fq * 8];
#pragma unroll
    for (int fn = 0; fn < 4; fn++) {
      int drow = fn * 16 + fl;
      int sw = 8 * (drow >> 3);
      short8 vf0 = *(const short8*)&vt[drow * 72 + ((fq * 8) ^ sw)];
      short8 vf1 = *(const short8*)&vt[drow * 72 + ((32 + fq * 8) ^ sw)];
      oacc[fn] = __builtin_amdgcn_mfma_f32_16x16x32_bf16(pf0, vf0, oacc[fn], 0, 0, 0);
      oacc[fn] = __builtin_amdgcn_mfma_f32_16x16x32_bf16(pf1, vf1, oacc[fn], 0, 0, 0);
    }
  }
  // X1 = X + O/l
#pragma unroll
  for (int fn = 0; fn < 4; fn++)
#pragma unroll
    for (int r = 0; r < 4; r++) {
      int qg = q0 + wave * 16 + fq * 4 + r;
      int d = fn * 16 + fl;
      size_t oi = ((size_t)b * T_ + qg) * C_ + hoff + d;
      X1[oi] = oacc[fn][r] / l[r] + X[oi];
    }
}

extern "C" void kernel_launch(void* const* d_in, const int* in_sizes, int n_in,
                              void* d_out, int out_size, void* d_ws, size_t ws_size,
                              hipStream_t stream) {
  const float* x  = (const float*)d_in[0];
  const float* wq = (const float*)d_in[1];
  const float* wk = (const float*)d_in[2];
  const float* wv = (const float*)d_in[3];
  const float* w1 = (const float*)d_in[4];
  const float* b1 = (const float*)d_in[5];
  const float* w2 = (const float*)d_in[6];
  const float* b2 = (const float*)d_in[7];
  const float* ln1g = (const float*)d_in[8];
  const float* ln1b = (const float*)d_in[9];
  const float* ln2g = (const float*)d_in[10];
  const float* ln2b = (const float*)d_in[11];
  ushort_t* ws = (ushort_t*)d_ws;

  const size_t SZ = (size_t)M_ * C_;   // 4,194,304 elems
  // ws: qkvt 786432 | w1t 1048576 | w2t 1048576 | qkv 3*SZ  (30.9 MB total)
  //   h2 reuses qkv[0,SZ); ff1 reuses qkv[SZ,3SZ)  (qkv dead after flash)
  ushort_t* qkvt = ws;
  ushort_t* w1t  = qkvt + 786432;
  ushort_t* w2t  = w1t + 1048576;
  ushort_t* qkv  = w2t + 1048576;
  ushort_t* h2   = qkv;
  ushort_t* ff1  = qkv + SZ;
  ushort_t* h    = (ushort_t*)d_out;   // LN1 out (bf16); dead before flash
  float* x1      = (float*)d_out;      // fp32 residual-1 & final out
  float* outf    = (float*)d_out;

  // weights -> bf16 [N][K] (Q rows 0..511, K rows 512..1023, V rows 1024..1535)
  transpose_k<<<dim3(2, 16, 8), 256, 0, stream>>>(wq, qkvt, 512, 64);
  transpose_k<<<dim3(2, 16, 8), 256, 0, stream>>>(wk, qkvt + 262144, 512, 64);
  transpose_k<<<dim3(2, 16, 8), 256, 0, stream>>>(wv, qkvt + 524288, 512, 64);
  transpose_k<<<dim3(64, 16, 1), 256, 0, stream>>>(w1, w1t, 512, 2048);
  transpose_k<<<dim3(16, 64, 1), 256, 0, stream>>>(w2, w2t, 2048, 512);

  // LN1: x (fp32) -> h (bf16, in d_out)
  ln_k<<<M_ / 4, 256, 0, stream>>>(x, ln1g, ln1b, h);
  // fused QKV: [8192,512] x [1536,512]^T -> qkv [8192,1536]
  gemm_bt128<<<dim3(12, 64, 1), 256, 0, stream>>>(h, qkvt, qkv, 0, 512, 512, 1536,
                                                  nullptr, 0);
  // attention + residual(x) -> x1 (fp32, d_out); 1024 blocks, heavy first
  flash_attn<<<B_ * H_ * (T_ / 64), 256, 0, stream>>>(qkv, x, x1);
  // LN2: x1 -> h2 (bf16)
  ln_k<<<M_ / 4, 256, 0, stream>>>(x1, ln2g, ln2b, h2);
  // FFN in two half-row passes (M=4096): ff1 = relu(h2*w1+b1);
  // out = x1 + b2 (init) + ff1*w2 (K-split x4, atomic)
  for (int p = 0; p < 2; p++) {
    const size_t roff = (size_t)p * 4096;
    gemm_bt128<<<dim3(16, 32, 1), 256, 0, stream>>>(h2 + roff * C_, w1t, ff1, 0,
                                                    512, 512, 2048, b1, 1);
    init_out_k<<<8192, 256, 0, stream>>>(outf + roff * C_, b2, 4096 * C_);
    gemm_bt128<<<dim3(4, 32, 4), 256, 0, stream>>>(ff1, w2t, outf + roff * C_, 2,
                                                   2048, 512, 512, nullptr, 0);
  }
}